// Round 5
// baseline (110.490 us; speedup 1.0000x reference)
//
#include <hip/hip_runtime.h>

// ---------------- constants ----------------
// B=16, CIN=256, COUT=256, H=W=64, K=3, SDIM=128
// Separable reformulation:
//   out[b,co,p] = demod[b,co] * sum_{t,ci} wsh[t,co,ci] * y[b,ci,p+shift(t)]
//   wsh = conv_scale * w  (batch-independent!),  y = s[b,ci] * x[b,ci,p]
//   demod[b,co] = rsqrt( sum_ci G[co,ci] * s[b,ci]^2 + 1e-8 ),  G = sum_t wsh^2
// ws layout (bytes):
//   xpad  bf16 [16][66][66][256] : 0          .. 35,684,352   (holds y, padded NHWC)
//   wsh   bf16 [9][256][256]     : 35,684,352 .. 36,864,000
//   s     f32  [16][256]         : 36,864,000 .. 36,880,384
//   G     f32  [256][256]        : 36,880,384 .. 37,142,528
//   demod f32  [16][256]         : 37,142,528 .. 37,158,912

#define WSH_OFF    35684352
#define S_OFF      36864000
#define G_OFF      36880384
#define DEMOD_OFF  37142528

typedef __attribute__((ext_vector_type(8))) short bf16x8;
typedef __attribute__((ext_vector_type(4))) float f32x4;
typedef __attribute__((ext_vector_type(4))) int i32x4;

#define GLOAD_LDS16(g, l)                                                        \
  __builtin_amdgcn_global_load_lds(                                              \
      (const __attribute__((address_space(1))) void*)(g),                        \
      (__attribute__((address_space(3))) void*)(l), 16, 0, 0)

__device__ __forceinline__ unsigned short f2bf(float f) {
  unsigned int u = __builtin_bit_cast(unsigned int, f);
  u += 0x7FFFu + ((u >> 16) & 1u);  // round-to-nearest-even
  return (unsigned short)(u >> 16);
}

// ---------------- kernel 1: style s[b][i]  +  shared weights & G ----------------
__global__ void prep1_k(const float* __restrict__ c_trg,
                        const float* __restrict__ style_w,
                        const float* __restrict__ style_b,
                        const float* __restrict__ weight,
                        float* __restrict__ s,
                        short* __restrict__ wsh,
                        float* __restrict__ G) {
  const int blk = blockIdx.x;
  const int tid = threadIdx.x;
  if (blk < 16) {
    const int b = blk;
    const float* ct = c_trg + b * 128;
    const float* sw = style_w + tid * 128;
    float acc = 0.f;
#pragma unroll 4
    for (int d = 0; d < 128; ++d) acc += ct[d] * sw[d];
    s[b * 256 + tid] = acc * 0.08838834764831845f + style_b[tid];  // 1/sqrt(128)
  } else {
    const int idx = (blk - 16) * 256 + tid;  // co*256+ci
    const float* wsrc = weight + idx * 9;    // 9 contiguous taps
    float g = 0.f;
#pragma unroll
    for (int t = 0; t < 9; ++t) {
      float v = wsrc[t] * 0.020833333333333332f;  // 1/sqrt(2304)
      g += v * v;
      wsh[t * 65536 + idx] = (short)f2bf(v);
    }
    G[idx] = g;
  }
}

// ---------------- kernel 2: demod[b][co] ----------------
__global__ void demod_k(const float* __restrict__ G,
                        const float* __restrict__ s,
                        float* __restrict__ demod) {
  const int bid = blockIdx.x;  // b*256 + co
  const int b = bid >> 8, co = bid & 255;
  const int t = threadIdx.x;
  const float sv = s[b * 256 + t];
  float ss = G[co * 256 + t] * sv * sv;
#pragma unroll
  for (int o = 32; o; o >>= 1) ss += __shfl_down(ss, o);
  __shared__ float red[4];
  if ((t & 63) == 0) red[t >> 6] = ss;
  __syncthreads();
  if (t == 0) demod[bid] = rsqrtf(red[0] + red[1] + red[2] + red[3] + 1e-8f);
}

// ---------------- kernel 3: y = s*x, fp32 NCHW -> bf16 padded NHWC; + border zero ----
__global__ void xpose_k(const float* __restrict__ x,
                        const float* __restrict__ s,
                        short* __restrict__ xpad) {
  __shared__ float tile[64][65];
  const int bid = blockIdx.x;
  const int tid = threadIdx.x;
  if (bid >= 4096) {
    const int b = bid - 4096;
    char* base = (char*)xpad + b * 66 * 66 * 512;
    const i32x4 z = {0, 0, 0, 0};
    for (int i = tid; i < 4224; i += 256) {
      const int r = i >= 2112;
      const int off = r * (65 * 66 * 512) + (i - r * 2112) * 16;
      *(i32x4*)(base + off) = z;
    }
    for (int i = tid; i < 4096; i += 256) {
      const int h = 1 + (i >> 6);
      const int side = (i >> 5) & 1;
      const int j = i & 31;
      *(i32x4*)(base + (h * 66 + side * 65) * 512 + j * 16) = z;
    }
    return;
  }
  const int ct = bid & 3;
  const int h = (bid >> 2) & 63;
  const int b = bid >> 8;
  const int w = tid & 63, cl = tid >> 6;
  const float* src = x + ((b * 256 + ct * 64) * 64 + h) * 64;
#pragma unroll
  for (int i = 0; i < 16; ++i) {
    int c = i * 4 + cl;
    tile[c][w] = src[c * 4096 + w];
  }
  const int cp = tid & 31;
  const float s0 = s[b * 256 + ct * 64 + cp * 2];
  const float s1 = s[b * 256 + ct * 64 + cp * 2 + 1];
  __syncthreads();
  short* dst = xpad + ((b * 66 + h + 1) * 66 + 1) * 256 + ct * 64;
#pragma unroll
  for (int i = 0; i < 8; ++i) {
    int idx = i * 256 + tid;
    int w2 = idx >> 5;  // 0..63
    unsigned int u = (unsigned int)f2bf(tile[cp * 2][w2] * s0) |
                     ((unsigned int)f2bf(tile[cp * 2 + 1][w2] * s1) << 16);
    *(unsigned int*)(dst + w2 * 256 + cp * 2) = u;
  }
}

// ---------------- kernel 4: implicit-GEMM conv, 256x256 tile, BK=32, 4-buf pipeline ---
// 512 thr = 8 waves (2M x 4N). LDS = 4 bufs x (A 16KB + B 16KB) = 128 KiB.
// 72 K-tiles (tap 0..8 x cc 0..7). Tile t lives in buf t&3; prefetch depth 3.
// Per tile: ONE barrier, counted vmcnt(8), two co-scheduled phases:
//   phase0: 8 ds_read (af0-3,bfr0-3) + gload A(t+3); lgkmcnt(0)+SB; 16 MFMA
//           (compiler free to interleave phase1 ds_reads/gloads into the MFMAs)
//   phase1: 4 ds_read (af4-7) + gload B(t+3); lgkmcnt(0)+SB; 16 MFMA
// Race-freedom: buf (t+3)&3 = tile t-1's buffer; all its reads drained
// (lgkmcnt(0)) before every wave passed this iter's barrier. vmcnt FIFO: at
// iter t, in-flight = tiles t,t+1,t+2 (12 loads); vmcnt(8) retires exactly t.
// BK=32 (64-B rows): ds_read_b128 pattern hits all 8 bank-groups evenly ->
// conflict-free with NO swizzle; gload_lds dest linear.
// T1: XCD swizzle (grid 256) -> 2 samples per XCD L2.
__global__ __launch_bounds__(512, 2) void conv_k(const short* __restrict__ xpad,
                                                 const short* __restrict__ wsh,
                                                 const float* __restrict__ demod,
                                                 float* __restrict__ out) {
  extern __shared__ __align__(16) char lds[];  // 131072 B

  const int tid = threadIdx.x;
  const int lane = tid & 63;
  const int wid = tid >> 6;
  const int wm = wid >> 2;   // 0..1 : cout half
  const int wn = wid & 3;    // 0..3 : pixel quarter (output row r0+wn)

  const int orig = blockIdx.x;
  const int bid = (orig & 7) * 32 + (orig >> 3);  // T1
  const int b = bid >> 4;
  const int r0 = (bid & 15) * 4;  // 4 output rows per block

  // staging source offsets (16 KB half per gload-pair; chunk g = i*512+tid):
  //   row = i*128 + (tid>>2), 16B col = (tid&3)*16
  const int t2 = tid >> 2;
  const int c4b = (tid & 3) * 16;
  const int aO0 = t2 * 512 + c4b;           // + tap*131072 + cc*64
  const int aO1 = aO0 + 65536;              // rows 128..255
  const int bO0 = ((b * 66 + r0 + (t2 >> 6)) * 66 + (t2 & 63)) * 512 + c4b;
  const int bO1 = bO0 + 67584;              // +2 rows (2*66*512)
  const char* wB = (const char*)wsh;
  const char* xB = (const char*)xpad;

  // read addresses: row-major [256][32] bf16 (64-B rows), frag row = lane&15,
  // k-chunk = lane>>4. No swizzle needed (bank-balanced).
  const int aRdBase = (wm * 128 + (lane & 15)) * 64 + (lane >> 4) * 16;
  const int bRdBase = 16384 + (wn * 64 + (lane & 15)) * 64 + (lane >> 4) * 16;

  f32x4 acc[8][4] = {};

  // prologue: stage tiles 0,1,2 (A-half then B-half each; FIFO order matters)
#pragma unroll
  for (int t = 0; t < 3; ++t) {
    const int cc = t;  // tiles 0..2 are tap 0, cc 0..2
    const int aAdd = cc * 64;
    const int bAdd = cc * 64;  // tap 0: dh=0,dw=0
    char* dA = lds + t * 32768;
    GLOAD_LDS16(wB + aAdd + aO0, dA + tid * 16);
    GLOAD_LDS16(wB + aAdd + aO1, dA + 8192 + tid * 16);
    GLOAD_LDS16(xB + bAdd + bO0, dA + 16384 + tid * 16);
    GLOAD_LDS16(xB + bAdd + bO1, dA + 24576 + tid * 16);
  }

  for (int t = 0; t < 72; ++t) {
    if (t < 70)       asm volatile("s_waitcnt vmcnt(8)" ::: "memory");
    else if (t == 70) asm volatile("s_waitcnt vmcnt(4)" ::: "memory");
    else              asm volatile("s_waitcnt vmcnt(0)" ::: "memory");
    __builtin_amdgcn_s_barrier();
    __builtin_amdgcn_sched_barrier(0);

    const char* Ab = lds + (t & 3) * 32768 + aRdBase;
    const char* Bb = lds + (t & 3) * 32768 + bRdBase;
    bf16x8 af[8], bfr[4];
#pragma unroll
    for (int m = 0; m < 4; ++m) af[m] = *(const bf16x8*)(Ab + m * 1024);
#pragma unroll
    for (int n = 0; n < 4; ++n) bfr[n] = *(const bf16x8*)(Bb + n * 1024);

    const int ts = t + 3;
    if (ts < 72) {  // stage A-half of tile t+3 into buf (t+3)&3 (tile t-1's, free)
      const int tap = ts >> 3, cc = ts & 7;
      const int aAdd = tap * 131072 + cc * 64;
      char* dA = lds + (ts & 3) * 32768;
      asm volatile("" ::: "memory");
      GLOAD_LDS16(wB + aAdd + aO0, dA + tid * 16);
      GLOAD_LDS16(wB + aAdd + aO1, dA + 8192 + tid * 16);
    }

    asm volatile("s_waitcnt lgkmcnt(0)" ::: "memory");
    __builtin_amdgcn_sched_barrier(0);
    __builtin_amdgcn_s_setprio(1);
#pragma unroll
    for (int m = 0; m < 4; ++m)
#pragma unroll
      for (int n = 0; n < 4; ++n)
        acc[m][n] = __builtin_amdgcn_mfma_f32_16x16x32_bf16(af[m], bfr[n], acc[m][n], 0, 0, 0);
    __builtin_amdgcn_s_setprio(0);

#pragma unroll
    for (int m = 4; m < 8; ++m) af[m] = *(const bf16x8*)(Ab + m * 1024);
    if (ts < 72) {  // stage B-half of tile t+3
      const int tap = ts >> 3, cc = ts & 7;
      const int dh = (tap * 11) >> 5;
      const int bAdd = (dh * 66 + (tap - dh * 3)) * 512 + cc * 64;
      char* dB = lds + (ts & 3) * 32768 + 16384;
      asm volatile("" ::: "memory");
      GLOAD_LDS16(xB + bAdd + bO0, dB + tid * 16);
      GLOAD_LDS16(xB + bAdd + bO1, dB + 8192 + tid * 16);
    }

    asm volatile("s_waitcnt lgkmcnt(0)" ::: "memory");
    __builtin_amdgcn_sched_barrier(0);
    __builtin_amdgcn_s_setprio(1);
#pragma unroll
    for (int m = 4; m < 8; ++m)
#pragma unroll
      for (int n = 0; n < 4; ++n)
        acc[m][n] = __builtin_amdgcn_mfma_f32_16x16x32_bf16(af[m], bfr[n], acc[m][n], 0, 0, 0);
    __builtin_amdgcn_s_setprio(0);
  }

  // epilogue: scale by demod[b][cout], store fp32 NCHW.
  const int pc = lane & 15;
  const int rOff = (lane >> 4) * 4;
  const int h = r0 + wn;
#pragma unroll
  for (int m = 0; m < 8; ++m) {
#pragma unroll
    for (int r = 0; r < 4; ++r) {
      const int co = wm * 128 + m * 16 + rOff + r;
      const float dm = demod[(b << 8) + co];
      float* orow = out + (((b << 8) + co) << 12) + (h << 6);
#pragma unroll
      for (int n = 0; n < 4; ++n) {
        orow[n * 16 + pc] = acc[m][n][r] * dm;
      }
    }
  }
}

// ---------------- launcher ----------------
extern "C" void kernel_launch(void* const* d_in, const int* in_sizes, int n_in,
                              void* d_out, int out_size, void* d_ws, size_t ws_size,
                              hipStream_t stream) {
  const float* x       = (const float*)d_in[0];
  // d_in[1] = c_src (unused by reference)
  const float* c_trg   = (const float*)d_in[2];
  const float* style_w = (const float*)d_in[3];
  const float* style_b = (const float*)d_in[4];
  const float* weight  = (const float*)d_in[5];
  float* out = (float*)d_out;

  char* ws = (char*)d_ws;
  short* xpad  = (short*)(ws);
  short* wsh   = (short*)(ws + WSH_OFF);
  float* s     = (float*)(ws + S_OFF);
  float* G     = (float*)(ws + G_OFF);
  float* demod = (float*)(ws + DEMOD_OFF);

  hipFuncSetAttribute((const void*)conv_k,
                      hipFuncAttributeMaxDynamicSharedMemorySize, 131072);

  prep1_k<<<272, 256, 0, stream>>>(c_trg, style_w, style_b, weight, s, wsh, G);
  demod_k<<<4096, 256, 0, stream>>>(G, s, demod);
  xpose_k<<<4112, 256, 0, stream>>>(x, s, xpad);
  conv_k<<<256, 512, 131072, stream>>>(xpad, wsh, demod, out);
}

// Round 6
// 101.849 us; speedup vs baseline: 1.0848x; 1.0848x over previous
//
#include <hip/hip_runtime.h>

// ---------------- constants ----------------
// B=16, CIN=256, COUT=256, H=W=64, K=3, SDIM=128
// Separable reformulation:
//   out[b,co,p] = demod[b,co] * sum_{t,ci} wsh[t,co,ci] * y[b,ci,p+shift(t)]
//   wsh = conv_scale * w  (batch-independent!),  y = s[b,ci] * x[b,ci,p]
//   demod[b,co] = rsqrt( sum_ci G[co,ci] * s[b,ci]^2 + 1e-8 ),  G = sum_t wsh^2
// ws layout (bytes):
//   xpad  bf16 [16][66][66][256] : 0          .. 35,684,352   (holds y, padded NHWC)
//   wsh   bf16 [9][256][256]     : 35,684,352 .. 36,864,000
//   s     f32  [16][256]         : 36,864,000 .. 36,880,384
//   G     f32  [256][256]        : 36,880,384 .. 37,142,528
//   demod f32  [16][256]         : 37,142,528 .. 37,158,912

#define WSH_OFF    35684352
#define S_OFF      36864000
#define G_OFF      36880384
#define DEMOD_OFF  37142528

typedef __attribute__((ext_vector_type(8))) short bf16x8;
typedef __attribute__((ext_vector_type(4))) float f32x4;
typedef __attribute__((ext_vector_type(4))) int i32x4;

#define GLOAD_LDS16(g, l)                                                        \
  __builtin_amdgcn_global_load_lds(                                              \
      (const __attribute__((address_space(1))) void*)(g),                        \
      (__attribute__((address_space(3))) void*)(l), 16, 0, 0)

__device__ __forceinline__ unsigned short f2bf(float f) {
  unsigned int u = __builtin_bit_cast(unsigned int, f);
  u += 0x7FFFu + ((u >> 16) & 1u);  // round-to-nearest-even
  return (unsigned short)(u >> 16);
}

// ---------------- kernel 1: style s[b][i]  +  shared weights & G ----------------
__global__ void prep1_k(const float* __restrict__ c_trg,
                        const float* __restrict__ style_w,
                        const float* __restrict__ style_b,
                        const float* __restrict__ weight,
                        float* __restrict__ s,
                        short* __restrict__ wsh,
                        float* __restrict__ G) {
  const int blk = blockIdx.x;
  const int tid = threadIdx.x;
  if (blk < 16) {
    const int b = blk;
    const float* ct = c_trg + b * 128;
    const float* sw = style_w + tid * 128;
    float acc = 0.f;
#pragma unroll 4
    for (int d = 0; d < 128; ++d) acc += ct[d] * sw[d];
    s[b * 256 + tid] = acc * 0.08838834764831845f + style_b[tid];  // 1/sqrt(128)
  } else {
    const int idx = (blk - 16) * 256 + tid;  // co*256+ci
    const float* wsrc = weight + idx * 9;    // 9 contiguous taps
    float g = 0.f;
#pragma unroll
    for (int t = 0; t < 9; ++t) {
      float v = wsrc[t] * 0.020833333333333332f;  // 1/sqrt(2304)
      g += v * v;
      wsh[t * 65536 + idx] = (short)f2bf(v);
    }
    G[idx] = g;
  }
}

// ---------------- kernel 2: y = s*x transpose + border zero + demod (fused grid) ----
// blocks 0..4095: transpose 64c x 64w tile via LDS.
// blocks 4096..4111: zero borders.
// blocks 4112..8207: demod[b][co].
__global__ void xpose_k(const float* __restrict__ x,
                        const float* __restrict__ s,
                        const float* __restrict__ G,
                        short* __restrict__ xpad,
                        float* __restrict__ demod) {
  __shared__ float tile[64][65];
  const int bid = blockIdx.x;
  const int tid = threadIdx.x;
  if (bid >= 4112) {
    // demod: block = b*256+co
    const int id = bid - 4112;
    const int b = id >> 8, co = id & 255;
    const float sv = s[b * 256 + tid];
    float ss = G[co * 256 + tid] * sv * sv;
#pragma unroll
    for (int o = 32; o; o >>= 1) ss += __shfl_down(ss, o);
    __shared__ float red[4];
    if ((tid & 63) == 0) red[tid >> 6] = ss;
    __syncthreads();
    if (tid == 0) demod[id] = rsqrtf(red[0] + red[1] + red[2] + red[3] + 1e-8f);
    return;
  }
  if (bid >= 4096) {
    const int b = bid - 4096;
    char* base = (char*)xpad + b * 66 * 66 * 512;
    const i32x4 z = {0, 0, 0, 0};
    for (int i = tid; i < 4224; i += 256) {
      const int r = i >= 2112;
      const int off = r * (65 * 66 * 512) + (i - r * 2112) * 16;
      *(i32x4*)(base + off) = z;
    }
    for (int i = tid; i < 4096; i += 256) {
      const int h = 1 + (i >> 6);
      const int side = (i >> 5) & 1;
      const int j = i & 31;
      *(i32x4*)(base + (h * 66 + side * 65) * 512 + j * 16) = z;
    }
    return;
  }
  const int ct = bid & 3;
  const int h = (bid >> 2) & 63;
  const int b = bid >> 8;
  const int w = tid & 63, cl = tid >> 6;
  const float* src = x + ((b * 256 + ct * 64) * 64 + h) * 64;
#pragma unroll
  for (int i = 0; i < 16; ++i) {
    int c = i * 4 + cl;
    tile[c][w] = src[c * 4096 + w];
  }
  const int cp = tid & 31;
  const float s0 = s[b * 256 + ct * 64 + cp * 2];
  const float s1 = s[b * 256 + ct * 64 + cp * 2 + 1];
  __syncthreads();
  short* dst = xpad + ((b * 66 + h + 1) * 66 + 1) * 256 + ct * 64;
#pragma unroll
  for (int i = 0; i < 8; ++i) {
    int idx = i * 256 + tid;
    int w2 = idx >> 5;  // 0..63
    unsigned int u = (unsigned int)f2bf(tile[cp * 2][w2] * s0) |
                     ((unsigned int)f2bf(tile[cp * 2 + 1][w2] * s1) << 16);
    *(unsigned int*)(dst + w2 * 256 + cp * 2) = u;
  }
}

// ---------------- kernel 3: implicit-GEMM conv, 256x256, BK=64, 4-phase/K-tile -------
// 512 thr = 8 waves (2M x 4N), wave tile 128x64. LDS = 2 dbuf x (A 32K + B 32K).
// 36 K-tiles (tap 0..8 x cc 0..3). m201-style schedule, 4 quadrant phases per tile:
//   ph0: ds_read A[m0-3]x2kc (8) + B[n0-1]x2kc (4); stage A(t+1);
//        barrier; lgkmcnt(0); 16 MFMA (m0-3 x n0-1); barrier
//   ph1: ds_read B[n2-3]x2kc (4);                 stage B(t+1);
//        barrier; lgkmcnt(0); 16 MFMA (m0-3 x n2-3); barrier
//   ph2: ds_read A[m4-7]x2kc (8);
//        barrier; lgkmcnt(0); 16 MFMA (m4-7 x n0-1); barrier
//   ph3: 16 MFMA (m4-7 x n2-3); vmcnt(0); barrier
// Double-barrier per phase keeps all 8 waves alternating LDS-phase/MFMA-phase
// (the m201 lever: 62% MfmaUtil on identical geometry). vmcnt(0) at ph3 drains
// loads issued 2-3 phases (~600-900cy) earlier -> near-zero stall; the barrier
// after it publishes every wave's staged LDS before any wave's next ds_read.
// T1: XCD swizzle (grid 256) -> 2 samples per XCD L2.
// T2: XOR swizzle byte ^= ((row&7)<<4): linear LDS dest, inverse-swizzled
//     global source, swizzled ds_read (the 128-B-row layout measured 0 conflicts).
__global__ __launch_bounds__(512, 2) void conv_k(const short* __restrict__ xpad,
                                                 const short* __restrict__ wsh,
                                                 const float* __restrict__ demod,
                                                 float* __restrict__ out) {
  extern __shared__ __align__(16) char lds[];  // 131072 B

  const int tid = threadIdx.x;
  const int lane = tid & 63;
  const int wid = tid >> 6;
  const int wm = wid >> 2;   // 0..1 : cout half
  const int wn = wid & 3;    // 0..3 : pixel quarter (output row r0+wn)

  const int orig = blockIdx.x;
  const int bid = (orig & 7) * 32 + (orig >> 3);  // T1
  const int b = bid >> 4;
  const int r0 = (bid & 15) * 4;  // 4 output rows per block

  // staging: per K-tile 8 x 16B loads/thread (A j0-3, B j0-3).
  // load j covers LDS rows j*64 + t3, byte col (tid&7)*16 (linear dest);
  // source col pre-swizzled: c16 ^ ((row&7)<<4), row&7 == t3&7.
  const int t3 = tid >> 3;
  const int c16 = (tid & 7) * 16;
  const int swzc = c16 ^ ((t3 & 7) << 4);
  int aO[4], bO[4];
#pragma unroll
  for (int j = 0; j < 4; ++j) {
    aO[j] = (j * 64 + t3) * 512 + swzc;                   // + tap*131072 + cc*128
    bO[j] = ((b * 66 + r0 + j) * 66 + t3) * 512 + swzc;   // + (dh*66+dw)*512 + cc*128
  }
  const char* wB = (const char*)wsh;
  const char* xB = (const char*)xpad;

  auto stageA = [&](int ts) {
    const int tap = ts >> 2, cc = ts & 3;
    const int aAdd = tap * 131072 + cc * 128;
    char* d = lds + (ts & 1) * 65536;
#pragma unroll
    for (int j = 0; j < 4; ++j)
      GLOAD_LDS16(wB + aAdd + aO[j], d + j * 8192 + tid * 16);
  };
  auto stageB = [&](int ts) {
    const int tap = ts >> 2, cc = ts & 3;
    const int dh = (tap * 11) >> 5;  // tap/3
    const int bAdd = (dh * 66 + (tap - dh * 3)) * 512 + cc * 128;
    char* d = lds + (ts & 1) * 65536 + 32768;
#pragma unroll
    for (int j = 0; j < 4; ++j)
      GLOAD_LDS16(xB + bAdd + bO[j], d + j * 8192 + tid * 16);
  };

  // T2 read side: col_read = col ^ ((row&7)<<4); row&7 == lane&7 everywhere.
  const int xall = (lane & 7) << 4;
  const int xl = xall & 0x30;
  const int xh = xall & 0x40;
  const int colR = (((lane >> 4) << 4) ^ xl);
  const int ko0 = xh;
  const int ko1 = 64 ^ xh;
  const int aRdBase = (wm * 128 + (lane & 15)) * 128 + colR;
  const int bRdBase = 32768 + (wn * 64 + (lane & 15)) * 128 + colR;

  f32x4 acc[8][4] = {};

  stageA(0);
  stageB(0);
  asm volatile("s_waitcnt vmcnt(0)" ::: "memory");
  __builtin_amdgcn_s_barrier();
  asm volatile("" ::: "memory");

  for (int t = 0; t < 36; ++t) {
    const char* Ab = lds + (t & 1) * 65536 + aRdBase;
    const char* Bb = lds + (t & 1) * 65536 + bRdBase;
    bf16x8 af[4][2], bq[2][2], bq2[2][2];

    // ---------- phase 0 ----------
#pragma unroll
    for (int m = 0; m < 4; ++m) {
      af[m][0] = *(const bf16x8*)(Ab + m * 2048 + ko0);
      af[m][1] = *(const bf16x8*)(Ab + m * 2048 + ko1);
    }
#pragma unroll
    for (int n = 0; n < 2; ++n) {
      bq[n][0] = *(const bf16x8*)(Bb + n * 2048 + ko0);
      bq[n][1] = *(const bf16x8*)(Bb + n * 2048 + ko1);
    }
    if (t + 1 < 36) stageA(t + 1);
    __builtin_amdgcn_s_barrier();
    asm volatile("s_waitcnt lgkmcnt(0)" ::: "memory");
    __builtin_amdgcn_sched_barrier(0);
    __builtin_amdgcn_s_setprio(1);
#pragma unroll
    for (int m = 0; m < 4; ++m)
#pragma unroll
      for (int n = 0; n < 2; ++n) {
        acc[m][n] = __builtin_amdgcn_mfma_f32_16x16x32_bf16(af[m][0], bq[n][0], acc[m][n], 0, 0, 0);
        acc[m][n] = __builtin_amdgcn_mfma_f32_16x16x32_bf16(af[m][1], bq[n][1], acc[m][n], 0, 0, 0);
      }
    __builtin_amdgcn_s_setprio(0);
    __builtin_amdgcn_s_barrier();

    // ---------- phase 1 ----------
#pragma unroll
    for (int n = 0; n < 2; ++n) {
      bq2[n][0] = *(const bf16x8*)(Bb + (n + 2) * 2048 + ko0);
      bq2[n][1] = *(const bf16x8*)(Bb + (n + 2) * 2048 + ko1);
    }
    if (t + 1 < 36) stageB(t + 1);
    __builtin_amdgcn_s_barrier();
    asm volatile("s_waitcnt lgkmcnt(0)" ::: "memory");
    __builtin_amdgcn_sched_barrier(0);
    __builtin_amdgcn_s_setprio(1);
#pragma unroll
    for (int m = 0; m < 4; ++m)
#pragma unroll
      for (int n = 0; n < 2; ++n) {
        acc[m][n + 2] = __builtin_amdgcn_mfma_f32_16x16x32_bf16(af[m][0], bq2[n][0], acc[m][n + 2], 0, 0, 0);
        acc[m][n + 2] = __builtin_amdgcn_mfma_f32_16x16x32_bf16(af[m][1], bq2[n][1], acc[m][n + 2], 0, 0, 0);
      }
    __builtin_amdgcn_s_setprio(0);
    __builtin_amdgcn_s_barrier();

    // ---------- phase 2 ----------
#pragma unroll
    for (int m = 0; m < 4; ++m) {
      af[m][0] = *(const bf16x8*)(Ab + (m + 4) * 2048 + ko0);
      af[m][1] = *(const bf16x8*)(Ab + (m + 4) * 2048 + ko1);
    }
    __builtin_amdgcn_s_barrier();
    asm volatile("s_waitcnt lgkmcnt(0)" ::: "memory");
    __builtin_amdgcn_sched_barrier(0);
    __builtin_amdgcn_s_setprio(1);
#pragma unroll
    for (int m = 0; m < 4; ++m)
#pragma unroll
      for (int n = 0; n < 2; ++n) {
        acc[m + 4][n] = __builtin_amdgcn_mfma_f32_16x16x32_bf16(af[m][0], bq[n][0], acc[m + 4][n], 0, 0, 0);
        acc[m + 4][n] = __builtin_amdgcn_mfma_f32_16x16x32_bf16(af[m][1], bq[n][1], acc[m + 4][n], 0, 0, 0);
      }
    __builtin_amdgcn_s_setprio(0);
    __builtin_amdgcn_s_barrier();

    // ---------- phase 3 (no reads) ----------
    __builtin_amdgcn_s_setprio(1);
#pragma unroll
    for (int m = 0; m < 4; ++m)
#pragma unroll
      for (int n = 0; n < 2; ++n) {
        acc[m + 4][n + 2] = __builtin_amdgcn_mfma_f32_16x16x32_bf16(af[m][0], bq2[n][0], acc[m + 4][n + 2], 0, 0, 0);
        acc[m + 4][n + 2] = __builtin_amdgcn_mfma_f32_16x16x32_bf16(af[m][1], bq2[n][1], acc[m + 4][n + 2], 0, 0, 0);
      }
    __builtin_amdgcn_s_setprio(0);
    asm volatile("s_waitcnt vmcnt(0)" ::: "memory");
    __builtin_amdgcn_s_barrier();
    asm volatile("" ::: "memory");
  }

  // epilogue: scale by demod[b][cout], store fp32 NCHW.
  const int pc = lane & 15;
  const int rOff = (lane >> 4) * 4;
  const int h = r0 + wn;
#pragma unroll
  for (int m = 0; m < 8; ++m) {
#pragma unroll
    for (int r = 0; r < 4; ++r) {
      const int co = wm * 128 + m * 16 + rOff + r;
      const float dm = demod[(b << 8) + co];
      float* orow = out + (((b << 8) + co) << 12) + (h << 6);
#pragma unroll
      for (int n = 0; n < 4; ++n) {
        orow[n * 16 + pc] = acc[m][n][r] * dm;
      }
    }
  }
}

// ---------------- launcher ----------------
extern "C" void kernel_launch(void* const* d_in, const int* in_sizes, int n_in,
                              void* d_out, int out_size, void* d_ws, size_t ws_size,
                              hipStream_t stream) {
  const float* x       = (const float*)d_in[0];
  // d_in[1] = c_src (unused by reference)
  const float* c_trg   = (const float*)d_in[2];
  const float* style_w = (const float*)d_in[3];
  const float* style_b = (const float*)d_in[4];
  const float* weight  = (const float*)d_in[5];
  float* out = (float*)d_out;

  char* ws = (char*)d_ws;
  short* xpad  = (short*)(ws);
  short* wsh   = (short*)(ws + WSH_OFF);
  float* s     = (float*)(ws + S_OFF);
  float* G     = (float*)(ws + G_OFF);
  float* demod = (float*)(ws + DEMOD_OFF);

  hipFuncSetAttribute((const void*)conv_k,
                      hipFuncAttributeMaxDynamicSharedMemorySize, 131072);

  prep1_k<<<272, 256, 0, stream>>>(c_trg, style_w, style_b, weight, s, wsh, G);
  xpose_k<<<8208, 256, 0, stream>>>(x, s, G, xpad, demod);
  conv_k<<<256, 512, 131072, stream>>>(xpad, wsh, demod, out);
}

// Round 7
// 96.469 us; speedup vs baseline: 1.1453x; 1.0558x over previous
//
#include <hip/hip_runtime.h>

// ---------------- constants ----------------
// B=16, CIN=256, COUT=256, H=W=64, K=3, SDIM=128
// Separable reformulation:
//   out[b,co,p] = demod[b,co] * sum_{t,ci} wsh[t,co,ci] * y[b,ci,p+shift(t)]
//   wsh = conv_scale * w  (batch-independent!),  y = s[b,ci] * x[b,ci,p]
//   demod[b,co] = rsqrt( sum_ci G[co,ci] * s[b,ci]^2 + 1e-8 ),  G = sum_t wsh^2
// ws layout (bytes):
//   xpad  bf16 [16][66][66][256] : 0          .. 35,684,352   (holds y, padded NHWC)
//   wsh   bf16 [9][256][256]     : 35,684,352 .. 36,864,000
//   s     f32  [16][256]         : 36,864,000 .. 36,880,384
//   G     f32  [256][256]        : 36,880,384 .. 37,142,528
//   demod f32  [16][256]         : 37,142,528 .. 37,158,912

#define WSH_OFF    35684352
#define S_OFF      36864000
#define G_OFF      36880384
#define DEMOD_OFF  37142528

typedef __attribute__((ext_vector_type(8))) short bf16x8;
typedef __attribute__((ext_vector_type(4))) float f32x4;
typedef __attribute__((ext_vector_type(4))) int i32x4;

#define GLOAD_LDS16(g, l)                                                        \
  __builtin_amdgcn_global_load_lds(                                              \
      (const __attribute__((address_space(1))) void*)(g),                        \
      (__attribute__((address_space(3))) void*)(l), 16, 0, 0)

__device__ __forceinline__ unsigned short f2bf(float f) {
  unsigned int u = __builtin_bit_cast(unsigned int, f);
  u += 0x7FFFu + ((u >> 16) & 1u);  // round-to-nearest-even
  return (unsigned short)(u >> 16);
}

// ---------------- kernel 1: style s[b][i]  +  shared weights & G ----------------
__global__ void prep1_k(const float* __restrict__ c_trg,
                        const float* __restrict__ style_w,
                        const float* __restrict__ style_b,
                        const float* __restrict__ weight,
                        float* __restrict__ s,
                        short* __restrict__ wsh,
                        float* __restrict__ G) {
  const int blk = blockIdx.x;
  const int tid = threadIdx.x;
  if (blk < 16) {
    const int b = blk;
    const float* ct = c_trg + b * 128;
    const float* sw = style_w + tid * 128;
    float acc = 0.f;
#pragma unroll 4
    for (int d = 0; d < 128; ++d) acc += ct[d] * sw[d];
    s[b * 256 + tid] = acc * 0.08838834764831845f + style_b[tid];  // 1/sqrt(128)
  } else {
    const int idx = (blk - 16) * 256 + tid;  // co*256+ci
    const float* wsrc = weight + idx * 9;    // 9 contiguous taps
    float g = 0.f;
#pragma unroll
    for (int t = 0; t < 9; ++t) {
      float v = wsrc[t] * 0.020833333333333332f;  // 1/sqrt(2304)
      g += v * v;
      wsh[t * 65536 + idx] = (short)f2bf(v);
    }
    G[idx] = g;
  }
}

// ---------------- kernel 2: y = s*x transpose + border zero + demod (fused grid) ----
__global__ void xpose_k(const float* __restrict__ x,
                        const float* __restrict__ s,
                        const float* __restrict__ G,
                        short* __restrict__ xpad,
                        float* __restrict__ demod) {
  __shared__ float tile[64][65];
  const int bid = blockIdx.x;
  const int tid = threadIdx.x;
  if (bid >= 4112) {
    // demod: block = b*256+co
    const int id = bid - 4112;
    const int b = id >> 8, co = id & 255;
    const float sv = s[b * 256 + tid];
    float ss = G[co * 256 + tid] * sv * sv;
#pragma unroll
    for (int o = 32; o; o >>= 1) ss += __shfl_down(ss, o);
    __shared__ float red[4];
    if ((tid & 63) == 0) red[tid >> 6] = ss;
    __syncthreads();
    if (tid == 0) demod[id] = rsqrtf(red[0] + red[1] + red[2] + red[3] + 1e-8f);
    return;
  }
  if (bid >= 4096) {
    const int b = bid - 4096;
    char* base = (char*)xpad + b * 66 * 66 * 512;
    const i32x4 z = {0, 0, 0, 0};
    for (int i = tid; i < 4224; i += 256) {
      const int r = i >= 2112;
      const int off = r * (65 * 66 * 512) + (i - r * 2112) * 16;
      *(i32x4*)(base + off) = z;
    }
    for (int i = tid; i < 4096; i += 256) {
      const int h = 1 + (i >> 6);
      const int side = (i >> 5) & 1;
      const int j = i & 31;
      *(i32x4*)(base + (h * 66 + side * 65) * 512 + j * 16) = z;
    }
    return;
  }
  const int ct = bid & 3;
  const int h = (bid >> 2) & 63;
  const int b = bid >> 8;
  const int w = tid & 63, cl = tid >> 6;
  const float* src = x + ((b * 256 + ct * 64) * 64 + h) * 64;
#pragma unroll
  for (int i = 0; i < 16; ++i) {
    int c = i * 4 + cl;
    tile[c][w] = src[c * 4096 + w];
  }
  const int cp = tid & 31;
  const float s0 = s[b * 256 + ct * 64 + cp * 2];
  const float s1 = s[b * 256 + ct * 64 + cp * 2 + 1];
  __syncthreads();
  short* dst = xpad + ((b * 66 + h + 1) * 66 + 1) * 256 + ct * 64;
#pragma unroll
  for (int i = 0; i < 8; ++i) {
    int idx = i * 256 + tid;
    int w2 = idx >> 5;  // 0..63
    unsigned int u = (unsigned int)f2bf(tile[cp * 2][w2] * s0) |
                     ((unsigned int)f2bf(tile[cp * 2 + 1][w2] * s1) << 16);
    *(unsigned int*)(dst + w2 * 256 + cp * 2) = u;
  }
}

// ---------------- kernel 3: implicit-GEMM conv, 256x256, BK=64, drift pipeline ------
// 512 thr = 8 waves (2M x 4N), wave tile 128x64. LDS = 2 dbuf x (A 32K + B 32K).
// 36 K-tiles (tap 0..8 x cc 0..3). ONE sync point per tile; waves drift freely
// inside the tile so one wave's MFMA burst overlaps its co-wave's ds_reads and
// staging (m114 overlap; setprio arbitrates). Continuous staging: tile t+1's
// A staged at ph0 of t, B at ph1 of t (depth-1, counted by the single vmcnt).
//   tile top: s_waitcnt vmcnt(0)   <- own stage(t) loads, issued ~600-900cy ago
//             s_barrier            <- publishes ALL waves' stage(t); retires
//                                     every read of buf t-1 (reads complete
//                                     before each wave's barrier arrival)
//   ph0: ds_read A0-3,B0-1 (12); stageA(t+1); lgkmcnt(0)+SB; 16 MFMA
//   ph1: ds_read B2-3 (4);       stageB(t+1); lgkmcnt(0)+SB; 16 MFMA
//   ph2: ds_read A4-7 (8);                    lgkmcnt(0)+SB; 16 MFMA
//   ph3: 16 MFMA
// Race-freedom: stage(t+1) targets buf (t+1)&1 = tile t-1's buffer; its reads
// were all consumed (lgkmcnt-waited) before their waves arrived at this tile's
// barrier. A drifting fast wave cannot read buf t+1 before the top-of-(t+1)
// barrier, which no wave passes until every wave staged AND vmcnt(0)-drained.
// T1: XCD swizzle (grid 256) -> 2 samples per XCD L2.
// T2: XOR swizzle byte ^= ((row&7)<<4): linear LDS dest, inverse-swizzled
//     global source, swizzled ds_read (measured 0 bank conflicts).
__global__ __launch_bounds__(512, 2) void conv_k(const short* __restrict__ xpad,
                                                 const short* __restrict__ wsh,
                                                 const float* __restrict__ demod,
                                                 float* __restrict__ out) {
  extern __shared__ __align__(16) char lds[];  // 131072 B

  const int tid = threadIdx.x;
  const int lane = tid & 63;
  const int wid = tid >> 6;
  const int wm = wid >> 2;   // 0..1 : cout half
  const int wn = wid & 3;    // 0..3 : pixel quarter (output row r0+wn)

  const int orig = blockIdx.x;
  const int bid = (orig & 7) * 32 + (orig >> 3);  // T1
  const int b = bid >> 4;
  const int r0 = (bid & 15) * 4;  // 4 output rows per block

  // staging: per K-tile 8 x 16B loads/thread (A j0-3, B j0-3).
  // load j covers LDS rows j*64 + t3, byte col (tid&7)*16 (linear dest);
  // source col pre-swizzled: c16 ^ ((row&7)<<4), row&7 == t3&7.
  const int t3 = tid >> 3;
  const int c16 = (tid & 7) * 16;
  const int swzc = c16 ^ ((t3 & 7) << 4);
  int aO[4], bO[4];
#pragma unroll
  for (int j = 0; j < 4; ++j) {
    aO[j] = (j * 64 + t3) * 512 + swzc;                   // + tap*131072 + cc*128
    bO[j] = ((b * 66 + r0 + j) * 66 + t3) * 512 + swzc;   // + (dh*66+dw)*512 + cc*128
  }
  const char* wB = (const char*)wsh;
  const char* xB = (const char*)xpad;

  auto stageA = [&](int ts) {
    const int tap = ts >> 2, cc = ts & 3;
    const int aAdd = tap * 131072 + cc * 128;
    char* d = lds + (ts & 1) * 65536;
#pragma unroll
    for (int j = 0; j < 4; ++j)
      GLOAD_LDS16(wB + aAdd + aO[j], d + j * 8192 + tid * 16);
  };
  auto stageB = [&](int ts) {
    const int tap = ts >> 2, cc = ts & 3;
    const int dh = (tap * 11) >> 5;  // tap/3
    const int bAdd = (dh * 66 + (tap - dh * 3)) * 512 + cc * 128;
    char* d = lds + (ts & 1) * 65536 + 32768;
#pragma unroll
    for (int j = 0; j < 4; ++j)
      GLOAD_LDS16(xB + bAdd + bO[j], d + j * 8192 + tid * 16);
  };

  // T2 read side: col_read = col ^ ((row&7)<<4); row&7 == lane&7 everywhere.
  const int xall = (lane & 7) << 4;
  const int xl = xall & 0x30;
  const int xh = xall & 0x40;
  const int colR = (((lane >> 4) << 4) ^ xl);
  const int ko0 = xh;
  const int ko1 = 64 ^ xh;
  const int aRdBase = (wm * 128 + (lane & 15)) * 128 + colR;
  const int bRdBase = 32768 + (wn * 64 + (lane & 15)) * 128 + colR;

  f32x4 acc[8][4] = {};

  stageA(0);
  stageB(0);

  for (int t = 0; t < 36; ++t) {
    // single sync point per K-tile
    asm volatile("s_waitcnt vmcnt(0)" ::: "memory");
    __builtin_amdgcn_s_barrier();
    __builtin_amdgcn_sched_barrier(0);

    const char* Ab = lds + (t & 1) * 65536 + aRdBase;
    const char* Bb = lds + (t & 1) * 65536 + bRdBase;
    bf16x8 af[4][2], bq[2][2], bq2[2][2];

    // ---------- phase 0 : reads A0-3,B0-1 ; stage A(t+1) ; MFMA quad (m0-3,n0-1) ----
#pragma unroll
    for (int m = 0; m < 4; ++m) {
      af[m][0] = *(const bf16x8*)(Ab + m * 2048 + ko0);
      af[m][1] = *(const bf16x8*)(Ab + m * 2048 + ko1);
    }
#pragma unroll
    for (int n = 0; n < 2; ++n) {
      bq[n][0] = *(const bf16x8*)(Bb + n * 2048 + ko0);
      bq[n][1] = *(const bf16x8*)(Bb + n * 2048 + ko1);
    }
    if (t + 1 < 36) stageA(t + 1);
    asm volatile("s_waitcnt lgkmcnt(0)" ::: "memory");
    __builtin_amdgcn_sched_barrier(0);
    __builtin_amdgcn_s_setprio(1);
#pragma unroll
    for (int m = 0; m < 4; ++m)
#pragma unroll
      for (int n = 0; n < 2; ++n) {
        acc[m][n] = __builtin_amdgcn_mfma_f32_16x16x32_bf16(af[m][0], bq[n][0], acc[m][n], 0, 0, 0);
        acc[m][n] = __builtin_amdgcn_mfma_f32_16x16x32_bf16(af[m][1], bq[n][1], acc[m][n], 0, 0, 0);
      }
    __builtin_amdgcn_s_setprio(0);

    // ---------- phase 1 : reads B2-3 ; stage B(t+1) ; MFMA quad (m0-3,n2-3) ---------
#pragma unroll
    for (int n = 0; n < 2; ++n) {
      bq2[n][0] = *(const bf16x8*)(Bb + (n + 2) * 2048 + ko0);
      bq2[n][1] = *(const bf16x8*)(Bb + (n + 2) * 2048 + ko1);
    }
    if (t + 1 < 36) stageB(t + 1);
    asm volatile("s_waitcnt lgkmcnt(0)" ::: "memory");
    __builtin_amdgcn_sched_barrier(0);
    __builtin_amdgcn_s_setprio(1);
#pragma unroll
    for (int m = 0; m < 4; ++m)
#pragma unroll
      for (int n = 0; n < 2; ++n) {
        acc[m][n + 2] = __builtin_amdgcn_mfma_f32_16x16x32_bf16(af[m][0], bq2[n][0], acc[m][n + 2], 0, 0, 0);
        acc[m][n + 2] = __builtin_amdgcn_mfma_f32_16x16x32_bf16(af[m][1], bq2[n][1], acc[m][n + 2], 0, 0, 0);
      }
    __builtin_amdgcn_s_setprio(0);

    // ---------- phase 2 : reads A4-7 ; MFMA quad (m4-7,n0-1) ------------------------
#pragma unroll
    for (int m = 0; m < 4; ++m) {
      af[m][0] = *(const bf16x8*)(Ab + (m + 4) * 2048 + ko0);
      af[m][1] = *(const bf16x8*)(Ab + (m + 4) * 2048 + ko1);
    }
    asm volatile("s_waitcnt lgkmcnt(0)" ::: "memory");
    __builtin_amdgcn_sched_barrier(0);
    __builtin_amdgcn_s_setprio(1);
#pragma unroll
    for (int m = 0; m < 4; ++m)
#pragma unroll
      for (int n = 0; n < 2; ++n) {
        acc[m + 4][n] = __builtin_amdgcn_mfma_f32_16x16x32_bf16(af[m][0], bq[n][0], acc[m + 4][n], 0, 0, 0);
        acc[m + 4][n] = __builtin_amdgcn_mfma_f32_16x16x32_bf16(af[m][1], bq[n][1], acc[m + 4][n], 0, 0, 0);
      }
    __builtin_amdgcn_s_setprio(0);

    // ---------- phase 3 : MFMA quad (m4-7,n2-3) -------------------------------------
    __builtin_amdgcn_s_setprio(1);
#pragma unroll
    for (int m = 0; m < 4; ++m)
#pragma unroll
      for (int n = 0; n < 2; ++n) {
        acc[m + 4][n + 2] = __builtin_amdgcn_mfma_f32_16x16x32_bf16(af[m][0], bq2[n][0], acc[m + 4][n + 2], 0, 0, 0);
        acc[m + 4][n + 2] = __builtin_amdgcn_mfma_f32_16x16x32_bf16(af[m][1], bq2[n][1], acc[m + 4][n + 2], 0, 0, 0);
      }
    __builtin_amdgcn_s_setprio(0);
    asm volatile("" ::: "memory");
  }

  // epilogue: scale by demod[b][cout], store fp32 NCHW.
  const int pc = lane & 15;
  const int rOff = (lane >> 4) * 4;
  const int h = r0 + wn;
#pragma unroll
  for (int m = 0; m < 8; ++m) {
#pragma unroll
    for (int r = 0; r < 4; ++r) {
      const int co = wm * 128 + m * 16 + rOff + r;
      const float dm = demod[(b << 8) + co];
      float* orow = out + (((b << 8) + co) << 12) + (h << 6);
#pragma unroll
      for (int n = 0; n < 4; ++n) {
        orow[n * 16 + pc] = acc[m][n][r] * dm;
      }
    }
  }
}

// ---------------- launcher ----------------
extern "C" void kernel_launch(void* const* d_in, const int* in_sizes, int n_in,
                              void* d_out, int out_size, void* d_ws, size_t ws_size,
                              hipStream_t stream) {
  const float* x       = (const float*)d_in[0];
  // d_in[1] = c_src (unused by reference)
  const float* c_trg   = (const float*)d_in[2];
  const float* style_w = (const float*)d_in[3];
  const float* style_b = (const float*)d_in[4];
  const float* weight  = (const float*)d_in[5];
  float* out = (float*)d_out;

  char* ws = (char*)d_ws;
  short* xpad  = (short*)(ws);
  short* wsh   = (short*)(ws + WSH_OFF);
  float* s     = (float*)(ws + S_OFF);
  float* G     = (float*)(ws + G_OFF);
  float* demod = (float*)(ws + DEMOD_OFF);

  hipFuncSetAttribute((const void*)conv_k,
                      hipFuncAttributeMaxDynamicSharedMemorySize, 131072);

  prep1_k<<<272, 256, 0, stream>>>(c_trg, style_w, style_b, weight, s, wsh, G);
  xpose_k<<<8208, 256, 0, stream>>>(x, s, G, xpad, demod);
  conv_k<<<256, 512, 131072, stream>>>(xpad, wsh, demod, out);
}